// Round 1
// baseline (1654.580 us; speedup 1.0000x reference)
//
#include <hip/hip_runtime.h>
#include <hip/hip_bf16.h>
#include <stdint.h>

typedef __bf16 bf16;
typedef __bf16 bf16x8 __attribute__((ext_vector_type(8)));
typedef float f32x4 __attribute__((ext_vector_type(4)));

#define HD 128
#define NTPB 4   // waves (16-row tiles) per block

__device__ inline float bflo(uint32_t u){ return __uint_as_float(u << 16); }
__device__ inline float bfhi(uint32_t u){ return __uint_as_float(u & 0xffff0000u); }
__device__ inline uint32_t packbf(float a, float b){
    bf16 x = (bf16)a, y = (bf16)b;
    uint16_t ux = __builtin_bit_cast(uint16_t, x), uy = __builtin_bit_cast(uint16_t, y);
    return (uint32_t)ux | ((uint32_t)uy << 16);
}
__device__ inline bf16x8 ldb8(const bf16* p){ return *(const bf16x8*)p; }

// ---------------- weight / activation conversion ----------------
__global__ void k_cvt(const float* __restrict__ in, bf16* __restrict__ out, int n){
    int i = blockIdx.x * 256 + threadIdx.x;
    if (i < n) out[i] = (bf16)in[i];
}

// ---------------- CSR build ----------------
__global__ void k_count(const int* __restrict__ dst, int* __restrict__ deg, int ne){
    int i = blockIdx.x * 256 + threadIdx.x;
    if (i < ne) atomicAdd(&deg[dst[i]], 1);
}

__global__ void k_scan1(const int* __restrict__ deg, int* __restrict__ rows,
                        int* __restrict__ bsum, int n){
    __shared__ int lds[256];
    int b = blockIdx.x, tid = threadIdx.x;
    int i0 = b * 1024 + tid * 4;
    int v[4]; int s = 0;
#pragma unroll
    for (int j = 0; j < 4; ++j){ int idx = i0 + j; v[j] = (idx < n) ? deg[idx] : 0; s += v[j]; }
    lds[tid] = s; __syncthreads();
    int acc = s;
    for (int off = 1; off < 256; off <<= 1){
        int add = (tid >= off) ? lds[tid - off] : 0;
        __syncthreads();
        acc += add; lds[tid] = acc;
        __syncthreads();
    }
    int run = acc - s;  // exclusive prefix for this thread's group
#pragma unroll
    for (int j = 0; j < 4; ++j){ int idx = i0 + j; if (idx < n) rows[idx] = run; run += v[j]; }
    if (tid == 255) bsum[b] = acc;
}

__global__ void k_scan2(int* __restrict__ bsum, int nb){
    __shared__ int lds[128];
    int tid = threadIdx.x;
    int v = (tid < nb) ? bsum[tid] : 0;
    lds[tid] = v; __syncthreads();
    int acc = v;
    for (int off = 1; off < 128; off <<= 1){
        int add = (tid >= off) ? lds[tid - off] : 0;
        __syncthreads();
        acc += add; lds[tid] = acc;
        __syncthreads();
    }
    if (tid < nb) bsum[tid] = acc - v;  // exclusive
}

__global__ void k_scan3(int* __restrict__ rows, const int* __restrict__ bsum, int n, int total){
    int i = blockIdx.x * 256 + threadIdx.x;
    if (i < n) rows[i] += bsum[i >> 10];
    if (i == n) rows[n] = total;
}

__global__ void k_fill(const int* __restrict__ src, const int* __restrict__ dst,
                       int* __restrict__ cur, int* __restrict__ col, int ne){
    int i = blockIdx.x * 256 + threadIdx.x;
    if (i < ne){ int p = atomicAdd(&cur[dst[i]], 1); col[p] = src[i]; }
}

// ---------------- mean aggregation: c = x + inv_deg * sum_{nb} x[nb] ----------------
__global__ __launch_bounds__(64) void k_gather(const bf16* __restrict__ curx,
                                               const int* __restrict__ rows,
                                               const int* __restrict__ col,
                                               bf16* __restrict__ cout, int n){
    int node = blockIdx.x;
    int lane = threadIdx.x;
    int s = rows[node], e = rows[node + 1];
    float inv = (e > s) ? 1.0f / (float)(e - s) : 0.0f;
    const uint32_t* base = (const uint32_t*)curx;
    float s0 = 0.f, s1 = 0.f;
    for (int i = s; i < e; ++i){
        int nb = col[i];
        uint32_t u = base[(size_t)nb * 64 + lane];
        s0 += bflo(u); s1 += bfhi(u);
    }
    uint32_t ux = base[(size_t)node * 64 + lane];
    float o0 = bflo(ux) + s0 * inv;
    float o1 = bfhi(ux) + s1 * inv;
    ((uint32_t*)cout)[(size_t)node * 64 + lane] = packbf(o0, o1);
}

// ---------------- MLP (Linear->ReLU->Linear) + BatchNorm, bf16 out ----------------
__global__ __launch_bounds__(256) void k_mlp(
    const bf16* __restrict__ cin, const bf16* __restrict__ W1, const float* __restrict__ b1,
    const bf16* __restrict__ W2, const float* __restrict__ b2,
    const float* __restrict__ gm, const float* __restrict__ bt,
    const float* __restrict__ mu, const float* __restrict__ vr,
    bf16* __restrict__ out, int nTiles)
{
    __shared__ bf16 lds[NTPB][16][HD];
    int wid = threadIdx.x >> 6, lane = threadIdx.x & 63;
    int tile = blockIdx.x * NTPB + wid;
    if (tile >= nTiles) return;
    int r0 = tile * 16;
    int rA = lane & 15, u = lane >> 4, ko = u * 8;

    bf16x8 a[4];
    const bf16* ap = cin + (size_t)(r0 + rA) * HD + ko;
#pragma unroll
    for (int kk = 0; kk < 4; ++kk) a[kk] = ldb8(ap + kk * 32);

#pragma unroll
    for (int t = 0; t < 8; ++t){
        f32x4 acc = {0.f, 0.f, 0.f, 0.f};
        int c = t * 16 + rA;
        const bf16* bp = W1 + (size_t)c * HD + ko;
#pragma unroll
        for (int kk = 0; kk < 4; ++kk)
            acc = __builtin_amdgcn_mfma_f32_16x16x32_bf16(a[kk], ldb8(bp + kk * 32), acc, 0, 0, 0);
        float bias = b1[c];
#pragma unroll
        for (int j = 0; j < 4; ++j){
            float v = acc[j] + bias;
            v = v > 0.f ? v : 0.f;
            lds[wid][u * 4 + j][c] = (bf16)v;
        }
    }
    __threadfence_block();  // order LDS writes before reads (wave-local)
    bf16x8 a2[4];
    const bf16* lp = &lds[wid][rA][ko];
#pragma unroll
    for (int kk = 0; kk < 4; ++kk) a2[kk] = ldb8(lp + kk * 32);

#pragma unroll
    for (int t = 0; t < 8; ++t){
        f32x4 acc = {0.f, 0.f, 0.f, 0.f};
        int c = t * 16 + rA;
        const bf16* bp = W2 + (size_t)c * HD + ko;
#pragma unroll
        for (int kk = 0; kk < 4; ++kk)
            acc = __builtin_amdgcn_mfma_f32_16x16x32_bf16(a2[kk], ldb8(bp + kk * 32), acc, 0, 0, 0);
        float s = gm[c] * rsqrtf(vr[c] + 1e-5f);
        float o = bt[c] - mu[c] * s;
        float bias = b2[c];
#pragma unroll
        for (int j = 0; j < 4; ++j)
            out[(size_t)(r0 + u * 4 + j) * HD + c] = (bf16)((acc[j] + bias) * s + o);
    }
}

// ---------------- GRU cell, in-place h update ----------------
__global__ __launch_bounds__(256) void k_gru(
    const bf16* __restrict__ cbn, bf16* __restrict__ h,
    const bf16* __restrict__ Wih, const bf16* __restrict__ Whh,
    const float* __restrict__ bih, const float* __restrict__ bhh, int nTiles)
{
    int wid = threadIdx.x >> 6, lane = threadIdx.x & 63;
    int tile = blockIdx.x * NTPB + wid;
    if (tile >= nTiles) return;
    int r0 = tile * 16;
    int rA = lane & 15, u = lane >> 4, ko = u * 8;

    bf16x8 ac[4], ah[4];
    const bf16* cp = cbn + (size_t)(r0 + rA) * HD + ko;
    const bf16* hp = h + (size_t)(r0 + rA) * HD + ko;
#pragma unroll
    for (int kk = 0; kk < 4; ++kk){ ac[kk] = ldb8(cp + kk * 32); ah[kk] = ldb8(hp + kk * 32); }

#pragma unroll
    for (int t = 0; t < 8; ++t){
        f32x4 accr = {0.f,0.f,0.f,0.f}, accz = {0.f,0.f,0.f,0.f};
        f32x4 gin  = {0.f,0.f,0.f,0.f}, ghn  = {0.f,0.f,0.f,0.f};
        int c = t * 16 + rA;
        const bf16* bri = Wih + (size_t)c * HD + ko;
        const bf16* bzi = Wih + (size_t)(c + 128) * HD + ko;
        const bf16* bni = Wih + (size_t)(c + 256) * HD + ko;
        const bf16* brh = Whh + (size_t)c * HD + ko;
        const bf16* bzh = Whh + (size_t)(c + 128) * HD + ko;
        const bf16* bnh = Whh + (size_t)(c + 256) * HD + ko;
#pragma unroll
        for (int kk = 0; kk < 4; ++kk){
            accr = __builtin_amdgcn_mfma_f32_16x16x32_bf16(ac[kk], ldb8(bri + kk * 32), accr, 0, 0, 0);
            accr = __builtin_amdgcn_mfma_f32_16x16x32_bf16(ah[kk], ldb8(brh + kk * 32), accr, 0, 0, 0);
            accz = __builtin_amdgcn_mfma_f32_16x16x32_bf16(ac[kk], ldb8(bzi + kk * 32), accz, 0, 0, 0);
            accz = __builtin_amdgcn_mfma_f32_16x16x32_bf16(ah[kk], ldb8(bzh + kk * 32), accz, 0, 0, 0);
            gin  = __builtin_amdgcn_mfma_f32_16x16x32_bf16(ac[kk], ldb8(bni + kk * 32), gin,  0, 0, 0);
            ghn  = __builtin_amdgcn_mfma_f32_16x16x32_bf16(ah[kk], ldb8(bnh + kk * 32), ghn,  0, 0, 0);
        }
        float br = bih[c] + bhh[c];
        float bz = bih[c + 128] + bhh[c + 128];
        float bin = bih[c + 256], bhn = bhh[c + 256];
#pragma unroll
        for (int j = 0; j < 4; ++j){
            size_t idx = (size_t)(r0 + u * 4 + j) * HD + c;
            float hold = (float)h[idx];
            float rg = 1.f / (1.f + __expf(-(accr[j] + br)));
            float zg = 1.f / (1.f + __expf(-(accz[j] + bz)));
            float ng = tanhf(gin[j] + bin + rg * (ghn[j] + bhn));
            h[idx] = (bf16)((1.f - zg) * ng + zg * hold);
        }
    }
}

// ---------------- final MLP: 128 -> 128 (ReLU) -> 64, f32 out ----------------
__global__ __launch_bounds__(256) void k_final(
    const bf16* __restrict__ hin, const bf16* __restrict__ W1, const float* __restrict__ b1,
    const bf16* __restrict__ W2, const float* __restrict__ b2,
    float* __restrict__ out, int nTiles)
{
    __shared__ bf16 lds[NTPB][16][HD];
    int wid = threadIdx.x >> 6, lane = threadIdx.x & 63;
    int tile = blockIdx.x * NTPB + wid;
    if (tile >= nTiles) return;
    int r0 = tile * 16;
    int rA = lane & 15, u = lane >> 4, ko = u * 8;

    bf16x8 a[4];
    const bf16* ap = hin + (size_t)(r0 + rA) * HD + ko;
#pragma unroll
    for (int kk = 0; kk < 4; ++kk) a[kk] = ldb8(ap + kk * 32);

#pragma unroll
    for (int t = 0; t < 8; ++t){
        f32x4 acc = {0.f, 0.f, 0.f, 0.f};
        int c = t * 16 + rA;
        const bf16* bp = W1 + (size_t)c * HD + ko;
#pragma unroll
        for (int kk = 0; kk < 4; ++kk)
            acc = __builtin_amdgcn_mfma_f32_16x16x32_bf16(a[kk], ldb8(bp + kk * 32), acc, 0, 0, 0);
        float bias = b1[c];
#pragma unroll
        for (int j = 0; j < 4; ++j){
            float v = acc[j] + bias;
            v = v > 0.f ? v : 0.f;
            lds[wid][u * 4 + j][c] = (bf16)v;
        }
    }
    __threadfence_block();
    bf16x8 a2[4];
    const bf16* lp = &lds[wid][rA][ko];
#pragma unroll
    for (int kk = 0; kk < 4; ++kk) a2[kk] = ldb8(lp + kk * 32);

#pragma unroll
    for (int t = 0; t < 4; ++t){
        f32x4 acc = {0.f, 0.f, 0.f, 0.f};
        int c = t * 16 + rA;
        const bf16* bp = W2 + (size_t)c * HD + ko;
#pragma unroll
        for (int kk = 0; kk < 4; ++kk)
            acc = __builtin_amdgcn_mfma_f32_16x16x32_bf16(a2[kk], ldb8(bp + kk * 32), acc, 0, 0, 0);
        float bias = b2[c];
#pragma unroll
        for (int j = 0; j < 4; ++j)
            out[(size_t)(r0 + u * 4 + j) * 64 + c] = acc[j] + bias;
    }
}

extern "C" void kernel_launch(void* const* d_in, const int* in_sizes, int n_in,
                              void* d_out, int out_size, void* d_ws, size_t ws_size,
                              hipStream_t stream)
{
    const float* x    = (const float*)d_in[0];
    const int*   src  = (const int*)d_in[1];
    const int*   dst  = (const int*)d_in[2];
    const float* lW1  = (const float*)d_in[3];
    const float* lb1  = (const float*)d_in[4];
    const float* lW2  = (const float*)d_in[5];
    const float* lb2  = (const float*)d_in[6];
    const float* gmm  = (const float*)d_in[7];
    const float* bta  = (const float*)d_in[8];
    const float* mun  = (const float*)d_in[9];
    const float* vrr  = (const float*)d_in[10];
    const float* Wih  = (const float*)d_in[11];
    const float* Whh  = (const float*)d_in[12];
    const float* bih  = (const float*)d_in[13];
    const float* bhh  = (const float*)d_in[14];
    const float* fW1  = (const float*)d_in[15];
    const float* fb1  = (const float*)d_in[16];
    const float* fW2  = (const float*)d_in[17];
    const float* fb2  = (const float*)d_in[18];

    int n  = in_sizes[0] / HD;       // 100000 nodes
    int ne = in_sizes[1];            // 2E directed edges
    int L  = in_sizes[3] / (HD * HD);

    char* w = (char*)d_ws;
    auto alloc = [&](size_t bytes) -> char* {
        char* p = w; w += (bytes + 255) & ~(size_t)255; return p;
    };
    bf16* xbf  = (bf16*)alloc((size_t)n * HD * 2);
    bf16* hbf  = (bf16*)alloc((size_t)n * HD * 2);
    bf16* cin  = (bf16*)alloc((size_t)n * HD * 2);
    bf16* cbn  = (bf16*)alloc((size_t)n * HD * 2);
    bf16* W1b  = (bf16*)alloc((size_t)L * HD * HD * 2);
    bf16* W2b  = (bf16*)alloc((size_t)L * HD * HD * 2);
    bf16* Wib  = (bf16*)alloc((size_t)3 * HD * HD * 2);
    bf16* Whb  = (bf16*)alloc((size_t)3 * HD * HD * 2);
    bf16* fW1b = (bf16*)alloc((size_t)HD * HD * 2);
    bf16* fW2b = (bf16*)alloc((size_t)64 * HD * 2);
    int*  deg  = (int*)alloc((size_t)n * 4);
    int*  rows = (int*)alloc((size_t)(n + 1) * 4);
    int*  bsum = (int*)alloc(512);
    int*  curi = (int*)alloc((size_t)n * 4);
    int*  col  = (int*)alloc((size_t)ne * 4);

    auto cvt = [&](const float* i, bf16* o, int cnt){
        k_cvt<<<(cnt + 255) / 256, 256, 0, stream>>>(i, o, cnt);
    };
    cvt(x,   xbf,  n * HD);
    cvt(lW1, W1b,  L * HD * HD);
    cvt(lW2, W2b,  L * HD * HD);
    cvt(Wih, Wib,  3 * HD * HD);
    cvt(Whh, Whb,  3 * HD * HD);
    cvt(fW1, fW1b, HD * HD);
    cvt(fW2, fW2b, 64 * HD);

    hipMemsetAsync(deg, 0, (size_t)n * 4, stream);
    hipMemsetAsync(hbf, 0, (size_t)n * HD * 2, stream);

    k_count<<<(ne + 255) / 256, 256, 0, stream>>>(dst, deg, ne);
    int nb = (n + 1023) / 1024;
    k_scan1<<<nb, 256, 0, stream>>>(deg, rows, bsum, n);
    k_scan2<<<1, 128, 0, stream>>>(bsum, nb);
    k_scan3<<<(n + 1 + 255) / 256, 256, 0, stream>>>(rows, bsum, n, ne);
    hipMemcpyAsync(curi, rows, (size_t)n * 4, hipMemcpyDeviceToDevice, stream);
    k_fill<<<(ne + 255) / 256, 256, 0, stream>>>(src, dst, curi, col, ne);

    int nTiles = (n + 15) / 16;
    int gB = (nTiles + NTPB - 1) / NTPB;
    const bf16* curp = xbf;
    for (int l = 0; l < L; ++l){
        k_gather<<<n, 64, 0, stream>>>(curp, rows, col, cin, n);
        k_mlp<<<gB, 256, 0, stream>>>(cin,
            W1b + (size_t)l * HD * HD, lb1 + l * HD,
            W2b + (size_t)l * HD * HD, lb2 + l * HD,
            gmm + l * HD, bta + l * HD, mun + l * HD, vrr + l * HD,
            cbn, nTiles);
        k_gru<<<gB, 256, 0, stream>>>(cbn, hbf, Wib, Whb, bih, bhh, nTiles);
        curp = hbf;
    }
    k_final<<<gB, 256, 0, stream>>>(hbf, fW1b, fb1, fW2b, fb2, (float*)d_out, nTiles);
}

// Round 2
// 1025.473 us; speedup vs baseline: 1.6135x; 1.6135x over previous
//
#include <hip/hip_runtime.h>
#include <hip/hip_bf16.h>
#include <stdint.h>

typedef __bf16 bf16;
typedef __bf16 bf16x8 __attribute__((ext_vector_type(8)));
typedef float f32x4 __attribute__((ext_vector_type(4)));
typedef uint32_t u32x4 __attribute__((ext_vector_type(4)));

#define HD 128
#define LDP (HD + 8)   // padded LDS row (elements) -> kills 8-way bank conflict on transpose stores
#define NTPB 4

__device__ inline float bflo(uint32_t u){ return __uint_as_float(u << 16); }
__device__ inline float bfhi(uint32_t u){ return __uint_as_float(u & 0xffff0000u); }
__device__ inline uint32_t packbf(float a, float b){
    bf16 x = (bf16)a, y = (bf16)b;
    uint16_t ux = __builtin_bit_cast(uint16_t, x), uy = __builtin_bit_cast(uint16_t, y);
    return (uint32_t)ux | ((uint32_t)uy << 16);
}
__device__ inline bf16x8 ldb8(const bf16* p){ return *(const bf16x8*)p; }
__device__ inline float sigm(float x){ return 1.f / (1.f + __expf(-x)); }
__device__ inline float tanh_fast(float x){ float t = __expf(-2.f * x); return (1.f - t) / (1.f + t); }

// ---------------- weight / activation conversion ----------------
__global__ void k_cvt(const float* __restrict__ in, bf16* __restrict__ out, int n){
    int i = blockIdx.x * 256 + threadIdx.x;
    if (i < n) out[i] = (bf16)in[i];
}

// ---------------- CSR (only the unsorted half needs building) ----------------
// rows2[v] = first index i in sorted dstB[0..E) with dstB[i] >= v
__global__ void k_bound(const int* __restrict__ dstB, int E, int* __restrict__ rows2, int n){
    int v = blockIdx.x * 256 + threadIdx.x;
    if (v > n) return;
    int lo = 0, hi = E;
    while (lo < hi){ int mid = (lo + hi) >> 1; if (dstB[mid] < v) lo = mid + 1; else hi = mid; }
    rows2[v] = lo;
}

__global__ void k_count(const int* __restrict__ dst, int* __restrict__ deg, int ne){
    int i = blockIdx.x * 256 + threadIdx.x;
    if (i < ne) atomicAdd(&deg[dst[i]], 1);
}

__global__ void k_scan1(const int* __restrict__ deg, int* __restrict__ rows,
                        int* __restrict__ bsum, int n){
    __shared__ int lds[256];
    int b = blockIdx.x, tid = threadIdx.x;
    int i0 = b * 1024 + tid * 4;
    int v[4]; int s = 0;
#pragma unroll
    for (int j = 0; j < 4; ++j){ int idx = i0 + j; v[j] = (idx < n) ? deg[idx] : 0; s += v[j]; }
    lds[tid] = s; __syncthreads();
    int acc = s;
    for (int off = 1; off < 256; off <<= 1){
        int add = (tid >= off) ? lds[tid - off] : 0;
        __syncthreads();
        acc += add; lds[tid] = acc;
        __syncthreads();
    }
    int run = acc - s;
#pragma unroll
    for (int j = 0; j < 4; ++j){ int idx = i0 + j; if (idx < n) rows[idx] = run; run += v[j]; }
    if (tid == 255) bsum[b] = acc;
}

__global__ void k_scan2(int* __restrict__ bsum, int nb){
    __shared__ int lds[128];
    int tid = threadIdx.x;
    int v = (tid < nb) ? bsum[tid] : 0;
    lds[tid] = v; __syncthreads();
    int acc = v;
    for (int off = 1; off < 128; off <<= 1){
        int add = (tid >= off) ? lds[tid - off] : 0;
        __syncthreads();
        acc += add; lds[tid] = acc;
        __syncthreads();
    }
    if (tid < nb) bsum[tid] = acc - v;
}

__global__ void k_scan3(int* __restrict__ rows, const int* __restrict__ bsum, int n, int total){
    int i = blockIdx.x * 256 + threadIdx.x;
    if (i < n) rows[i] += bsum[i >> 10];
    if (i == n) rows[n] = total;
}

__global__ void k_fill(const int* __restrict__ src, const int* __restrict__ dst,
                       int* __restrict__ cur, int* __restrict__ col, int ne){
    int i = blockIdx.x * 256 + threadIdx.x;
    if (i < ne){ int p = atomicAdd(&cur[dst[i]], 1); col[p] = src[i]; }
}

// ---------------- mean aggregation: c = x + inv_deg * sum_{nb} x[nb] ----------------
// Two neighbor segments per node v:
//   A: sorted-by-dst half -> ids read directly from srcB[rows2[v]..rows2[v+1])
//   B: scattered half     -> ids from colB[rowsB[v]..rowsB[v+1])
// 4 neighbors in flight per wave (16 lanes x 16B each), shfl_xor reduce.
__global__ __launch_bounds__(256) void k_gather(
    const bf16* __restrict__ curx,
    const int* __restrict__ srcB, const int* __restrict__ rows2,
    const int* __restrict__ colB, const int* __restrict__ rowsB,
    bf16* __restrict__ cout, int n)
{
    int wid = threadIdx.x >> 6, lane = threadIdx.x & 63;
    int v = blockIdx.x * 4 + wid;
    if (v >= n) return;
    int grp = lane >> 4, sl = lane & 15;
    int a0 = rows2[v], a1 = rows2[v + 1];
    int b0 = rowsB[v], b1 = rowsB[v + 1];
    int deg = (a1 - a0) + (b1 - b0);
    float inv = (deg > 0) ? 1.f / (float)deg : 0.f;

    const u32x4* base = (const u32x4*)curx;   // 16B per lane-slot; row = 32 u32x4? no: row=128bf16=16 u32x4? -> 128*2/16=16
    float acc[8];
#pragma unroll
    for (int k = 0; k < 8; ++k) acc[k] = 0.f;

    for (int j = a0 + grp; j < a1; j += 4){
        int nb = srcB[j];
        u32x4 q = base[(size_t)nb * 16 + sl];
#pragma unroll
        for (int k = 0; k < 4; ++k){ acc[2*k] += bflo(q[k]); acc[2*k+1] += bfhi(q[k]); }
    }
    for (int j = b0 + grp; j < b1; j += 4){
        int nb = colB[j];
        u32x4 q = base[(size_t)nb * 16 + sl];
#pragma unroll
        for (int k = 0; k < 4; ++k){ acc[2*k] += bflo(q[k]); acc[2*k+1] += bfhi(q[k]); }
    }
#pragma unroll
    for (int k = 0; k < 8; ++k){
        acc[k] += __shfl_xor(acc[k], 16);
        acc[k] += __shfl_xor(acc[k], 32);
    }
    if (grp == 0){
        u32x4 xv = base[(size_t)v * 16 + sl];
        u32x4 o;
#pragma unroll
        for (int k = 0; k < 4; ++k){
            float lo = bflo(xv[k]) + acc[2*k] * inv;
            float hi = bfhi(xv[k]) + acc[2*k+1] * inv;
            o[k] = packbf(lo, hi);
        }
        ((u32x4*)cout)[(size_t)v * 16 + sl] = o;
    }
}

// ---------------- fused Layer: MLP(GEMM-ReLU-GEMM) + BN + GRU, 32 rows/wave ----------------
__global__ __launch_bounds__(256) void k_layer(
    const bf16* __restrict__ cin, bf16* __restrict__ h,
    const bf16* __restrict__ W1, const float* __restrict__ b1,
    const bf16* __restrict__ W2, const float* __restrict__ b2,
    const float* __restrict__ gm, const float* __restrict__ bt,
    const float* __restrict__ mu, const float* __restrict__ vr,
    const bf16* __restrict__ Wih, const bf16* __restrict__ Whh,
    const float* __restrict__ bih, const float* __restrict__ bhh,
    int nT)
{
    __shared__ bf16 lds[4][32][LDP];
    int wid = threadIdx.x >> 6, lane = threadIdx.x & 63;
    int t32 = blockIdx.x * 4 + wid;
    if (t32 >= nT) return;
    int r0 = t32 * 32;
    int rA = lane & 15, u = lane >> 4, ko = u * 8;

    // ---- GEMM1 + ReLU -> LDS ----
    bf16x8 a[2][4];
#pragma unroll
    for (int m = 0; m < 2; ++m){
        const bf16* ap = cin + (size_t)(r0 + m*16 + rA) * HD + ko;
#pragma unroll
        for (int kk = 0; kk < 4; ++kk) a[m][kk] = ldb8(ap + kk * 32);
    }
#pragma unroll
    for (int t = 0; t < 8; ++t){
        int c = t * 16 + rA;
        const bf16* bp = W1 + (size_t)c * HD + ko;
        f32x4 acc0 = {0,0,0,0}, acc1 = {0,0,0,0};
#pragma unroll
        for (int kk = 0; kk < 4; ++kk){
            bf16x8 bfr = ldb8(bp + kk * 32);
            acc0 = __builtin_amdgcn_mfma_f32_16x16x32_bf16(a[0][kk], bfr, acc0, 0, 0, 0);
            acc1 = __builtin_amdgcn_mfma_f32_16x16x32_bf16(a[1][kk], bfr, acc1, 0, 0, 0);
        }
        float bias = b1[c];
#pragma unroll
        for (int j = 0; j < 4; ++j){
            float v0 = acc0[j] + bias; v0 = v0 > 0.f ? v0 : 0.f;
            float v1 = acc1[j] + bias; v1 = v1 > 0.f ? v1 : 0.f;
            lds[wid][u*4 + j][c]      = (bf16)v0;
            lds[wid][16 + u*4 + j][c] = (bf16)v1;
        }
    }
    __threadfence_block();

    // ---- GEMM2 + BN -> LDS ----
    bf16x8 a2[2][4];
#pragma unroll
    for (int m = 0; m < 2; ++m){
        const bf16* lp = &lds[wid][m*16 + rA][ko];
#pragma unroll
        for (int kk = 0; kk < 4; ++kk) a2[m][kk] = ldb8(lp + kk * 32);
    }
#pragma unroll
    for (int t = 0; t < 8; ++t){
        int c = t * 16 + rA;
        const bf16* bp = W2 + (size_t)c * HD + ko;
        f32x4 acc0 = {0,0,0,0}, acc1 = {0,0,0,0};
#pragma unroll
        for (int kk = 0; kk < 4; ++kk){
            bf16x8 bfr = ldb8(bp + kk * 32);
            acc0 = __builtin_amdgcn_mfma_f32_16x16x32_bf16(a2[0][kk], bfr, acc0, 0, 0, 0);
            acc1 = __builtin_amdgcn_mfma_f32_16x16x32_bf16(a2[1][kk], bfr, acc1, 0, 0, 0);
        }
        float s = gm[c] * rsqrtf(vr[c] + 1e-5f);
        float o = bt[c] - mu[c] * s;
        float bias = b2[c];
#pragma unroll
        for (int j = 0; j < 4; ++j){
            lds[wid][u*4 + j][c]      = (bf16)((acc0[j] + bias) * s + o);
            lds[wid][16 + u*4 + j][c] = (bf16)((acc1[j] + bias) * s + o);
        }
    }
    __threadfence_block();

    // ---- GRU ----
    bf16x8 ac[2][4], ah[2][4];
#pragma unroll
    for (int m = 0; m < 2; ++m){
        const bf16* lp = &lds[wid][m*16 + rA][ko];
        const bf16* hp = h + (size_t)(r0 + m*16 + rA) * HD + ko;
#pragma unroll
        for (int kk = 0; kk < 4; ++kk){ ac[m][kk] = ldb8(lp + kk * 32); ah[m][kk] = ldb8(hp + kk * 32); }
    }
#pragma unroll
    for (int t = 0; t < 8; ++t){
        int c = t * 16 + rA;
        const bf16* bri = Wih + (size_t)c * HD + ko;
        const bf16* bzi = bri + (size_t)128 * HD;
        const bf16* bni = bri + (size_t)256 * HD;
        const bf16* brh = Whh + (size_t)c * HD + ko;
        const bf16* bzh = brh + (size_t)128 * HD;
        const bf16* bnh = brh + (size_t)256 * HD;
        f32x4 rr0={0,0,0,0}, rr1={0,0,0,0}, zz0={0,0,0,0}, zz1={0,0,0,0};
        f32x4 gi0={0,0,0,0}, gi1={0,0,0,0}, gh0={0,0,0,0}, gh1={0,0,0,0};
#pragma unroll
        for (int kk = 0; kk < 4; ++kk){
            bf16x8 Bri = ldb8(bri + kk*32), Brh = ldb8(brh + kk*32);
            bf16x8 Bzi = ldb8(bzi + kk*32), Bzh = ldb8(bzh + kk*32);
            bf16x8 Bni = ldb8(bni + kk*32), Bnh = ldb8(bnh + kk*32);
            rr0 = __builtin_amdgcn_mfma_f32_16x16x32_bf16(ac[0][kk], Bri, rr0, 0, 0, 0);
            rr0 = __builtin_amdgcn_mfma_f32_16x16x32_bf16(ah[0][kk], Brh, rr0, 0, 0, 0);
            rr1 = __builtin_amdgcn_mfma_f32_16x16x32_bf16(ac[1][kk], Bri, rr1, 0, 0, 0);
            rr1 = __builtin_amdgcn_mfma_f32_16x16x32_bf16(ah[1][kk], Brh, rr1, 0, 0, 0);
            zz0 = __builtin_amdgcn_mfma_f32_16x16x32_bf16(ac[0][kk], Bzi, zz0, 0, 0, 0);
            zz0 = __builtin_amdgcn_mfma_f32_16x16x32_bf16(ah[0][kk], Bzh, zz0, 0, 0, 0);
            zz1 = __builtin_amdgcn_mfma_f32_16x16x32_bf16(ac[1][kk], Bzi, zz1, 0, 0, 0);
            zz1 = __builtin_amdgcn_mfma_f32_16x16x32_bf16(ah[1][kk], Bzh, zz1, 0, 0, 0);
            gi0 = __builtin_amdgcn_mfma_f32_16x16x32_bf16(ac[0][kk], Bni, gi0, 0, 0, 0);
            gi1 = __builtin_amdgcn_mfma_f32_16x16x32_bf16(ac[1][kk], Bni, gi1, 0, 0, 0);
            gh0 = __builtin_amdgcn_mfma_f32_16x16x32_bf16(ah[0][kk], Bnh, gh0, 0, 0, 0);
            gh1 = __builtin_amdgcn_mfma_f32_16x16x32_bf16(ah[1][kk], Bnh, gh1, 0, 0, 0);
        }
        float br = bih[c] + bhh[c];
        float bz = bih[c + 128] + bhh[c + 128];
        float bin = bih[c + 256], bhn = bhh[c + 256];
#pragma unroll
        for (int j = 0; j < 4; ++j){
            size_t i0 = (size_t)(r0 + u*4 + j) * HD + c;
            size_t i1 = (size_t)(r0 + 16 + u*4 + j) * HD + c;
            float h0 = (float)h[i0], h1 = (float)h[i1];
            float rg0 = sigm(rr0[j] + br), rg1 = sigm(rr1[j] + br);
            float zg0 = sigm(zz0[j] + bz), zg1 = sigm(zz1[j] + bz);
            float ng0 = tanh_fast(gi0[j] + bin + rg0 * (gh0[j] + bhn));
            float ng1 = tanh_fast(gi1[j] + bin + rg1 * (gh1[j] + bhn));
            h[i0] = (bf16)((1.f - zg0) * ng0 + zg0 * h0);
            h[i1] = (bf16)((1.f - zg1) * ng1 + zg1 * h1);
        }
    }
}

// ---------------- final MLP: 128 -> 128 (ReLU) -> 64, f32 out ----------------
__global__ __launch_bounds__(256) void k_final(
    const bf16* __restrict__ hin, const bf16* __restrict__ W1, const float* __restrict__ b1,
    const bf16* __restrict__ W2, const float* __restrict__ b2,
    float* __restrict__ out, int nTiles)
{
    __shared__ bf16 lds[NTPB][16][LDP];
    int wid = threadIdx.x >> 6, lane = threadIdx.x & 63;
    int tile = blockIdx.x * NTPB + wid;
    if (tile >= nTiles) return;
    int r0 = tile * 16;
    int rA = lane & 15, u = lane >> 4, ko = u * 8;

    bf16x8 a[4];
    const bf16* ap = hin + (size_t)(r0 + rA) * HD + ko;
#pragma unroll
    for (int kk = 0; kk < 4; ++kk) a[kk] = ldb8(ap + kk * 32);

#pragma unroll
    for (int t = 0; t < 8; ++t){
        f32x4 acc = {0.f, 0.f, 0.f, 0.f};
        int c = t * 16 + rA;
        const bf16* bp = W1 + (size_t)c * HD + ko;
#pragma unroll
        for (int kk = 0; kk < 4; ++kk)
            acc = __builtin_amdgcn_mfma_f32_16x16x32_bf16(a[kk], ldb8(bp + kk * 32), acc, 0, 0, 0);
        float bias = b1[c];
#pragma unroll
        for (int j = 0; j < 4; ++j){
            float v = acc[j] + bias;
            v = v > 0.f ? v : 0.f;
            lds[wid][u * 4 + j][c] = (bf16)v;
        }
    }
    __threadfence_block();
    bf16x8 a2[4];
    const bf16* lp = &lds[wid][rA][ko];
#pragma unroll
    for (int kk = 0; kk < 4; ++kk) a2[kk] = ldb8(lp + kk * 32);

#pragma unroll
    for (int t = 0; t < 4; ++t){
        f32x4 acc = {0.f, 0.f, 0.f, 0.f};
        int c = t * 16 + rA;
        const bf16* bp = W2 + (size_t)c * HD + ko;
#pragma unroll
        for (int kk = 0; kk < 4; ++kk)
            acc = __builtin_amdgcn_mfma_f32_16x16x32_bf16(a2[kk], ldb8(bp + kk * 32), acc, 0, 0, 0);
        float bias = b2[c];
#pragma unroll
        for (int j = 0; j < 4; ++j)
            out[(size_t)(r0 + u * 4 + j) * 64 + c] = acc[j] + bias;
    }
}

extern "C" void kernel_launch(void* const* d_in, const int* in_sizes, int n_in,
                              void* d_out, int out_size, void* d_ws, size_t ws_size,
                              hipStream_t stream)
{
    const float* x    = (const float*)d_in[0];
    const int*   src  = (const int*)d_in[1];
    const int*   dst  = (const int*)d_in[2];
    const float* lW1  = (const float*)d_in[3];
    const float* lb1  = (const float*)d_in[4];
    const float* lW2  = (const float*)d_in[5];
    const float* lb2  = (const float*)d_in[6];
    const float* gmm  = (const float*)d_in[7];
    const float* bta  = (const float*)d_in[8];
    const float* mun  = (const float*)d_in[9];
    const float* vrr  = (const float*)d_in[10];
    const float* Wih  = (const float*)d_in[11];
    const float* Whh  = (const float*)d_in[12];
    const float* bih  = (const float*)d_in[13];
    const float* bhh  = (const float*)d_in[14];
    const float* fW1  = (const float*)d_in[15];
    const float* fb1  = (const float*)d_in[16];
    const float* fW2  = (const float*)d_in[17];
    const float* fb2  = (const float*)d_in[18];

    int n  = in_sizes[0] / HD;       // 100000 nodes
    int ne = in_sizes[1];            // 2E directed edges
    int E  = ne / 2;                 // unique undirected edges; dst[E:2E) is SORTED
    int L  = in_sizes[3] / (HD * HD);

    char* w = (char*)d_ws;
    auto alloc = [&](size_t bytes) -> char* {
        char* p = w; w += (bytes + 255) & ~(size_t)255; return p;
    };
    bf16* xbf  = (bf16*)alloc((size_t)n * HD * 2);
    bf16* hbf  = (bf16*)alloc((size_t)n * HD * 2);
    bf16* cin  = (bf16*)alloc((size_t)n * HD * 2);
    bf16* W1b  = (bf16*)alloc((size_t)L * HD * HD * 2);
    bf16* W2b  = (bf16*)alloc((size_t)L * HD * HD * 2);
    bf16* Wib  = (bf16*)alloc((size_t)3 * HD * HD * 2);
    bf16* Whb  = (bf16*)alloc((size_t)3 * HD * HD * 2);
    bf16* fW1b = (bf16*)alloc((size_t)HD * HD * 2);
    bf16* fW2b = (bf16*)alloc((size_t)64 * HD * 2);
    int*  degB = (int*)alloc((size_t)n * 4);
    int*  rowsB= (int*)alloc((size_t)(n + 1) * 4);
    int*  rows2= (int*)alloc((size_t)(n + 1) * 4);
    int*  bsum = (int*)alloc(512);
    int*  curB = (int*)alloc((size_t)n * 4);
    int*  colB = (int*)alloc((size_t)E * 4);

    auto cvt = [&](const float* i, bf16* o, int cnt){
        k_cvt<<<(cnt + 255) / 256, 256, 0, stream>>>(i, o, cnt);
    };
    cvt(x,   xbf,  n * HD);
    cvt(lW1, W1b,  L * HD * HD);
    cvt(lW2, W2b,  L * HD * HD);
    cvt(Wih, Wib,  3 * HD * HD);
    cvt(Whh, Whb,  3 * HD * HD);
    cvt(fW1, fW1b, HD * HD);
    cvt(fW2, fW2b, 64 * HD);

    hipMemsetAsync(degB, 0, (size_t)n * 4, stream);
    hipMemsetAsync(hbf, 0, (size_t)n * HD * 2, stream);

    // sorted half: direct CSR by binary search (no build)
    k_bound<<<(n + 1 + 255) / 256, 256, 0, stream>>>(dst + E, E, rows2, n);
    // unsorted half: histogram + scan + atomic fill (E edges, half of before)
    k_count<<<(E + 255) / 256, 256, 0, stream>>>(dst, degB, E);
    int nb = (n + 1023) / 1024;
    k_scan1<<<nb, 256, 0, stream>>>(degB, rowsB, bsum, n);
    k_scan2<<<1, 128, 0, stream>>>(bsum, nb);
    k_scan3<<<(n + 1 + 255) / 256, 256, 0, stream>>>(rowsB, bsum, n, E);
    hipMemcpyAsync(curB, rowsB, (size_t)n * 4, hipMemcpyDeviceToDevice, stream);
    k_fill<<<(E + 255) / 256, 256, 0, stream>>>(src, dst, curB, colB, E);

    int nT32 = (n + 31) / 32;
    int gL = (nT32 + 3) / 4;
    int nT16 = (n + 15) / 16;
    int gF = (nT16 + NTPB - 1) / NTPB;

    const bf16* curp = xbf;
    for (int l = 0; l < L; ++l){
        k_gather<<<(n + 3) / 4, 256, 0, stream>>>(curp, src + E, rows2, colB, rowsB, cin, n);
        k_layer<<<gL, 256, 0, stream>>>(cin, hbf,
            W1b + (size_t)l * HD * HD, lb1 + l * HD,
            W2b + (size_t)l * HD * HD, lb2 + l * HD,
            gmm + l * HD, bta + l * HD, mun + l * HD, vrr + l * HD,
            Wib, Whb, bih, bhh, nT32);
        curp = hbf;
    }
    k_final<<<gF, 256, 0, stream>>>(hbf, fW1b, fb1, fW2b, fb2, (float*)d_out, nT16);
}